// Round 4
// baseline (585.604 us; speedup 1.0000x reference)
//
#include <hip/hip_runtime.h>
#include <stdint.h>

// Problem: N=8, d=o=16, F=512, NUM_LAYERS=3.  ALL fp32 (per reference).
// out[n,o,g] = LN_o( 0.5*(c1 + c2) )  where
//   c0 = einsum(x, W, A0); h1 = LN_o(c0)
//   c1 = einsum(x, W, A1); c2 = einsum(h1, W, A0)
// einsum(h,W,a)[n,o,g] = sum_{d,f} h[n,d,f] * W[d,f,g,o] * a[f,g]
// W (fp32) is 256 MB -> two streaming passes (c0+c1 share pass 1).
// Roofline: 2 x 256 MB at ~6.3 TB/s ~= 82 us + small kernels.
//
// R1: 2 cols/thread + launch_bounds cap -> scratch spills (WRITE 322MB). 
// R2: 1 col/thread + reg double-buffer -> ~160us/pass (1.6 TB/s).
// R3: x,A in LDS, same W feed -> ~150us/pass. Neutral.
// Diagnosis: per-lane VGPR-held W stream with depth-1 vmcnt wait never
//   achieves line rate; LDS broadcasts of x eat the latency-hiding slack.
// R4: canonical staging (guide §5 / T14): W tile global->reg (issued a full
//   step early) -> ds_write -> consume from LDS. Double-buffered 32KB slabs
//   keep a full tile in flight per block; 2 cols/thread cuts x-broadcast
//   cost per FMA 2x and W ds_reads are 2-way-aliased b64 (free).

#define FC   16    // f's per block (one f-slab per step)
#define NFCH 32    // 512 / FC

// K0: x (fp32, [n][d][f]) -> xT (fp32, [f][d][n])  (65536 elems)
__global__ void k0_prep_x(const float* __restrict__ x, float* __restrict__ xT) {
    int idx = blockIdx.x * blockDim.x + threadIdx.x;   // 0..65535
    int n = idx & 7, d = (idx >> 3) & 15, f = idx >> 7;
    xT[idx] = x[n * 8192 + d * 512 + f];
}

// K1 (PASS_A=true):  c0 partials (A[0]) + c1 partials (A[1]) from xT
// K3 (PASS_A=false): c2 partials (A[0]) from xT2, f reversed per chunk
//                    (serpentine) to harvest pass-1 L3 stream tails.
// grid = (32 f-chunks, 16 col-tiles) = 512 blocks = 2 blocks/CU (76KB LDS).
// Block covers 512 cols, 2 cols/thread. Per f-step stage [16d][512col] 32KB.
template <bool PASS_A>
__global__ __launch_bounds__(256)
void k_contract(const float* __restrict__ W, const float* __restrict__ A,
                const float* __restrict__ xT,
                float* __restrict__ p0, float* __restrict__ p1) {
    __shared__ float Wlds[2][16][512];   // 64 KB double-buffered W f-slab
    __shared__ float sx[FC][16][8];      //  8 KB x slices [f_local][d][n]
    __shared__ float sA[2][FC][32];      //  4 KB A slices [i][f_local][g_local]

    const int t  = threadIdx.x;          // 0..255
    const int fc = blockIdx.x;           // 0..31
    const int ct = blockIdx.y;           // 0..15
    const int f0 = fc * FC;

    // ---- stage x: FC*128 = 2048 floats (2 float4 per thread) ----
    {
        const float4* src = reinterpret_cast<const float4*>(xT + (size_t)f0 * 128);
        float4* dst = reinterpret_cast<float4*>(&sx[0][0][0]);
        dst[t]       = src[t];
        dst[t + 256] = src[t + 256];
    }
    // ---- stage A: [i][16 f][32 g] (float2 per thread per i) ----
    {
        int fl = t >> 4, gg = (t & 15) * 2;
        *reinterpret_cast<float2*>(&sA[0][fl][gg]) =
            *reinterpret_cast<const float2*>(&A[(size_t)(f0 + fl) * 512 + ct * 32 + gg]);
        if constexpr (PASS_A)
            *reinterpret_cast<float2*>(&sA[1][fl][gg]) =
                *reinterpret_cast<const float2*>(&A[262144 + (size_t)(f0 + fl) * 512 + ct * 32 + gg]);
    }

    // Staging geometry: slab flat-linear; thread t, instr k covers bytes
    // [k*4096 + t*16): row d = 2k + (t>=128), col = (t&127)*4.
    const int thf  = t >> 7;             // 0..1
    const int tcol = (t & 127) * 4;      // 0..508, step 4

    float c0x[8], c0y[8], c1x[8], c1y[8];
#pragma unroll
    for (int n = 0; n < 8; ++n) { c0x[n] = 0.f; c0y[n] = 0.f; c1x[n] = 0.f; c1y[n] = 0.f; }

    float4 g[8];
    // fl for step s (serpentine in pass B)
    auto FL = [&](int s) { return PASS_A ? s : (FC - 1 - s); };
    auto gload = [&](int s) {
        const int f = f0 + FL(s);
#pragma unroll
        for (int k = 0; k < 8; ++k)
            g[k] = *reinterpret_cast<const float4*>(
                W + (size_t)(2 * k + thf) * 4194304 + (size_t)f * 8192 + ct * 512 + tcol);
    };
    auto swrite = [&](int buf) {
#pragma unroll
        for (int k = 0; k < 8; ++k)
            *reinterpret_cast<float4*>(&Wlds[buf][2 * k + thf][tcol]) = g[k];
    };

    // prologue: slab 0 staged; slab 1's loads in flight
    gload(0);
    swrite(0);
    if (FC > 1) gload(1);
    __syncthreads();                     // sx, sA, Wlds[0] visible

#pragma unroll 2
    for (int ff = 0; ff < FC; ++ff) {
        const int fl  = FL(ff);
        const int cur = ff & 1;
        const float a0 = sA[0][fl][t >> 3];
        float a1 = 0.f;
        if constexpr (PASS_A) a1 = sA[1][fl][t >> 3];

        float px[8], py[8];
#pragma unroll
        for (int n = 0; n < 8; ++n) { px[n] = 0.f; py[n] = 0.f; }
#pragma unroll
        for (int d = 0; d < 16; ++d) {
            // 2 cols/thread: b64 read, lanes 8B-consecutive -> 2-way alias = free
            float2 w = *reinterpret_cast<const float2*>(&Wlds[cur][d][t * 2]);
            float4 xa = *reinterpret_cast<const float4*>(&sx[fl][d][0]);
            float4 xb = *reinterpret_cast<const float4*>(&sx[fl][d][4]);
            px[0] = fmaf(xa.x, w.x, px[0]);  py[0] = fmaf(xa.x, w.y, py[0]);
            px[1] = fmaf(xa.y, w.x, px[1]);  py[1] = fmaf(xa.y, w.y, py[1]);
            px[2] = fmaf(xa.z, w.x, px[2]);  py[2] = fmaf(xa.z, w.y, py[2]);
            px[3] = fmaf(xa.w, w.x, px[3]);  py[3] = fmaf(xa.w, w.y, py[3]);
            px[4] = fmaf(xb.x, w.x, px[4]);  py[4] = fmaf(xb.x, w.y, py[4]);
            px[5] = fmaf(xb.y, w.x, px[5]);  py[5] = fmaf(xb.y, w.y, py[5]);
            px[6] = fmaf(xb.z, w.x, px[6]);  py[6] = fmaf(xb.z, w.y, py[6]);
            px[7] = fmaf(xb.w, w.x, px[7]);  py[7] = fmaf(xb.w, w.y, py[7]);
        }
#pragma unroll
        for (int n = 0; n < 8; ++n) {
            c0x[n] = fmaf(a0, px[n], c0x[n]);
            c0y[n] = fmaf(a0, py[n], c0y[n]);
        }
        if constexpr (PASS_A) {
#pragma unroll
            for (int n = 0; n < 8; ++n) {
                c1x[n] = fmaf(a1, px[n], c1x[n]);
                c1y[n] = fmaf(a1, py[n], c1y[n]);
            }
        }

        if (ff + 1 < FC) {
            __syncthreads();             // all waves done reading buf[cur^1]'s old slab
            swrite(cur ^ 1);             // write next slab (vmcnt wait on g auto)
            if (ff + 2 < FC) gload(ff + 2);  // issue-early: full step to land
            __syncthreads();             // next slab visible
        }
    }

    // partials [fc][col][n]: thread's 2 cols x 8 n = 16 contiguous floats
    const int col = ct * 512 + t * 2;
    float4* dst0 = reinterpret_cast<float4*>(p0 + ((size_t)fc * 8192 + col) * 8);
    dst0[0] = make_float4(c0x[0], c0x[1], c0x[2], c0x[3]);
    dst0[1] = make_float4(c0x[4], c0x[5], c0x[6], c0x[7]);
    dst0[2] = make_float4(c0y[0], c0y[1], c0y[2], c0y[3]);
    dst0[3] = make_float4(c0y[4], c0y[5], c0y[6], c0y[7]);
    if constexpr (PASS_A) {
        float4* dst1 = reinterpret_cast<float4*>(p1 + ((size_t)fc * 8192 + col) * 8);
        dst1[0] = make_float4(c1x[0], c1x[1], c1x[2], c1x[3]);
        dst1[1] = make_float4(c1x[4], c1x[5], c1x[6], c1x[7]);
        dst1[2] = make_float4(c1y[0], c1y[1], c1y[2], c1y[3]);
        dst1[3] = make_float4(c1y[4], c1y[5], c1y[6], c1y[7]);
    }
}

// K2: reduce c0 partials over 32 chunks, LayerNorm over o, write h1 in
// xT-compatible layout: xT2[f=g][d=o][n]  (fp32)
__global__ __launch_bounds__(128)
void k_reduce_ln(const float* __restrict__ part, float* __restrict__ outT) {
    __shared__ float sh[16][8];
    int g = blockIdx.x;                 // 0..511
    int t = threadIdx.x;                // 0..127
    int o = t >> 3, n = t & 7;
    size_t base = ((size_t)g * 16 + o) * 8 + n;
    float s0 = 0.f, s1 = 0.f, s2 = 0.f, s3 = 0.f;
#pragma unroll
    for (int ch = 0; ch < NFCH; ch += 4) {
        s0 += part[(size_t)(ch + 0) * 65536 + base];
        s1 += part[(size_t)(ch + 1) * 65536 + base];
        s2 += part[(size_t)(ch + 2) * 65536 + base];
        s3 += part[(size_t)(ch + 3) * 65536 + base];
    }
    float s = (s0 + s1) + (s2 + s3);
    sh[o][n] = s;
    __syncthreads();
    float m = 0.f, v = 0.f;
#pragma unroll
    for (int oo = 0; oo < 16; ++oo) { float y = sh[oo][n]; m += y; v += y * y; }
    m *= (1.f / 16.f);
    v = v * (1.f / 16.f) - m * m;
    float r = rsqrtf(v + 1e-5f);
    outT[base] = (s - m) * r;
}

// K4: y = 0.5*(c1+c2) (reduced over chunks), LayerNorm over o, fp32 out [n][o][g]
__global__ __launch_bounds__(128)
void k_final(const float* __restrict__ p1, const float* __restrict__ p2,
             float* __restrict__ out) {
    __shared__ float sh[16][8];
    int g = blockIdx.x;
    int t = threadIdx.x;
    int o = t >> 3, n = t & 7;
    size_t base = ((size_t)g * 16 + o) * 8 + n;
    float s0 = 0.f, s1 = 0.f, s2 = 0.f, s3 = 0.f;
#pragma unroll
    for (int ch = 0; ch < NFCH; ch += 2) {
        size_t i0 = (size_t)(ch + 0) * 65536 + base;
        size_t i1 = (size_t)(ch + 1) * 65536 + base;
        s0 += p1[i0]; s1 += p2[i0];
        s2 += p1[i1]; s3 += p2[i1];
    }
    float s = 0.5f * ((s0 + s1) + (s2 + s3));
    sh[o][n] = s;
    __syncthreads();
    float m = 0.f, v = 0.f;
#pragma unroll
    for (int oo = 0; oo < 16; ++oo) { float y = sh[oo][n]; m += y; v += y * y; }
    m *= (1.f / 16.f);
    v = v * (1.f / 16.f) - m * m;
    float r = rsqrtf(v + 1e-5f);
    out[n * 8192 + o * 512 + g] = (s - m) * r;
}

extern "C" void kernel_launch(void* const* d_in, const int* in_sizes, int n_in,
                              void* d_out, int out_size, void* d_ws, size_t ws_size,
                              hipStream_t stream) {
    const float* x = (const float*)d_in[0];   // (8,16,512)      fp32
    const float* W = (const float*)d_in[1];   // (16,512,512,16) fp32
    const float* A = (const float*)d_in[2];   // (2,512,512)     fp32
    float* out = (float*)d_out;               // (8,16,512)      fp32

    float* ws  = (float*)d_ws;
    float* xT  = ws;                    //   65536 floats: x  transposed [f][d][n]
    float* xT2 = ws + 65536;            //   65536 floats: h1 transposed [f][d][n]
    float* c0p = ws + 131072;           // 2097152 floats: c0 partials [32][8192][8]
    float* c1p = c0p + 2097152;         // 2097152 floats: c1 partials
    float* c2p = c1p + 2097152;         // 2097152 floats: c2 partials
    // total ws use: ~26 MB

    k0_prep_x<<<256, 256, 0, stream>>>(x, xT);
    k_contract<true ><<<dim3(NFCH, 16), 256, 0, stream>>>(W, A, xT,  c0p, c1p);
    k_reduce_ln<<<512, 128, 0, stream>>>(c0p, xT2);
    k_contract<false><<<dim3(NFCH, 16), 256, 0, stream>>>(W, A, xT2, c2p, nullptr);
    k_final<<<512, 128, 0, stream>>>(c1p, c2p, out);
}

// Round 5
// 507.675 us; speedup vs baseline: 1.1535x; 1.1535x over previous
//
#include <hip/hip_runtime.h>
#include <stdint.h>

// Problem: N=8, d=o=16, F=512, NUM_LAYERS=3.  ALL fp32 (per reference).
// out[n,o,g] = LN_o( 0.5*(c1 + c2) )  where
//   c0 = einsum(x, W, A0); h1 = LN_o(c0)
//   c1 = einsum(x, W, A1); c2 = einsum(h1, W, A0)
// einsum(h,W,a)[n,o,g] = sum_{d,f} h[n,d,f] * W[d,f,g,o] * a[f,g]
// W (fp32) is 256 MB -> two streaming passes (c0+c1 share pass 1).
// Roofline: 2 x 256 MB at ~6.3 TB/s ~= 82 us + small kernels.
//
// Ladder so far (per contract pass):
//  R1 222us: reg-capped spills (WRITE 322MB). Lesson: never cap min-blocks.
//  R2 150us: 1 col/thr, x via batched s_loads -> scalar-fetch serialization.
//  R3 145us: 1 col/thr, x via LDS. Per (f,d): 24 LDS-cyc broadcast feeds only
//            512B of W -> LDS-pipe cap ~10 B/cyc/CU ~= measured 1.8 TB/s.
//  R4 193us: W through LDS too: 48 LDS reads + 2 barriers per step -> worse.
// Theory: the binding constraint is x-broadcast LDS cycles PER W-BYTE.
// R5: 4 cols/thread, float4 W loads (the m13-proven 16B/lane stream shape).
//     Same 2 broadcast reads now feed 2KB of W -> LDS cap ~42 B/cyc >> line
//     rate. 576 FMA-instr per f-iter > HBM latency -> compiler-scheduled
//     overlap suffices; no barriers in loop, no explicit prefetch, no cap.

#define FC   8     // f's per chunk
#define NFCH 64    // 512 / FC

// K0: x (fp32, [n][d][f]) -> xT (fp32, [f][d][n])  (65536 elems)
__global__ void k0_prep_x(const float* __restrict__ x, float* __restrict__ xT) {
    int idx = blockIdx.x * blockDim.x + threadIdx.x;   // 0..65535
    int n = idx & 7, d = (idx >> 3) & 15, f = idx >> 7;
    xT[idx] = x[n * 8192 + d * 512 + f];
}

// K1 (PASS_A=true):  c0 partials (A[0]) + c1 partials (A[1]) from xT
// K3 (PASS_A=false): c2 partials (A[0]) from xT2, f reversed per chunk
//                    (serpentine) to harvest pass-1 L3 stream tails.
// grid = (64 f-chunks, 8 col-groups) = 512 blocks = 2 blocks/CU.
// 4 cols/thread (float4), 256 threads -> 1024 cols per block.
// Partial layout: [chunk][col][n]  (32 contiguous floats per thread).
template <bool PASS_A>
__global__ __launch_bounds__(256)
void k_contract(const float* __restrict__ W, const float* __restrict__ A,
                const float* __restrict__ xT,
                float* __restrict__ p0, float* __restrict__ p1) {
    __shared__ float sx[FC][16][8];    // 4 KB  x slices [f_local][d][n]
    __shared__ float sA[2][FC][64];    // 4 KB  A slices [i][f_local][g_local]

    const int t   = threadIdx.x;       // 0..255
    const int fc  = blockIdx.x;        // 0..63
    const int cg  = blockIdx.y;        // 0..7
    const int f0  = fc * FC;
    const int col = cg * 1024 + t * 4; // 4 consecutive cols, same g
    const int gl  = t >> 2;            // g_local = g - cg*64, 0..63

    // ---- stage x: FC*128 = 1024 floats (1 float4 per thread) ----
    {
        const float4* src = reinterpret_cast<const float4*>(xT + (size_t)f0 * 128);
        reinterpret_cast<float4*>(&sx[0][0][0])[t] = src[t];
    }
    // ---- stage A: FC*64 = 512 floats per mat (1 float2 per thread) ----
    {
        int fl = t >> 5, gg = (t & 31) * 2;
        *reinterpret_cast<float2*>(&sA[0][fl][gg]) =
            *reinterpret_cast<const float2*>(&A[(size_t)(f0 + fl) * 512 + cg * 64 + gg]);
        if constexpr (PASS_A)
            *reinterpret_cast<float2*>(&sA[1][fl][gg]) =
                *reinterpret_cast<const float2*>(&A[262144 + (size_t)(f0 + fl) * 512 + cg * 64 + gg]);
    }
    __syncthreads();

    const float* Wc = W + col;         // + d*4194304 + f*8192

    float c0[4][8], c1[4][8];
#pragma unroll
    for (int c = 0; c < 4; ++c)
#pragma unroll
        for (int n = 0; n < 8; ++n) { c0[c][n] = 0.f; c1[c][n] = 0.f; }

#pragma unroll
    for (int ff = 0; ff < FC; ++ff) {
        const int fl = PASS_A ? ff : (FC - 1 - ff);   // serpentine in pass B
        const int f  = f0 + fl;

        // 16 independent float4 loads: wave streams 16 KB this iteration.
        // Fully unrolled loop + no barriers -> compiler overlaps next-iter
        // loads under this iter's 576 FMAs (which exceed HBM latency).
        float4 w[16];
#pragma unroll
        for (int d = 0; d < 16; ++d)
            w[d] = *reinterpret_cast<const float4*>(
                Wc + (size_t)d * 4194304 + (size_t)f * 8192);

        float p[4][8];
#pragma unroll
        for (int c = 0; c < 4; ++c)
#pragma unroll
            for (int n = 0; n < 8; ++n) p[c][n] = 0.f;

#pragma unroll
        for (int d = 0; d < 16; ++d) {
            // broadcast reads: 2 x ds_read_b128, uniform address, feed 2KB of W
            float4 xa = *reinterpret_cast<const float4*>(&sx[fl][d][0]);
            float4 xb = *reinterpret_cast<const float4*>(&sx[fl][d][4]);
#define FMA8(c, wc) \
            p[c][0] = fmaf(xa.x, wc, p[c][0]); \
            p[c][1] = fmaf(xa.y, wc, p[c][1]); \
            p[c][2] = fmaf(xa.z, wc, p[c][2]); \
            p[c][3] = fmaf(xa.w, wc, p[c][3]); \
            p[c][4] = fmaf(xb.x, wc, p[c][4]); \
            p[c][5] = fmaf(xb.y, wc, p[c][5]); \
            p[c][6] = fmaf(xb.z, wc, p[c][6]); \
            p[c][7] = fmaf(xb.w, wc, p[c][7]);
            FMA8(0, w[d].x)
            FMA8(1, w[d].y)
            FMA8(2, w[d].z)
            FMA8(3, w[d].w)
#undef FMA8
        }

        const float a0 = sA[0][fl][gl];
#pragma unroll
        for (int c = 0; c < 4; ++c)
#pragma unroll
            for (int n = 0; n < 8; ++n) c0[c][n] = fmaf(a0, p[c][n], c0[c][n]);
        if constexpr (PASS_A) {
            const float a1 = sA[1][fl][gl];
#pragma unroll
            for (int c = 0; c < 4; ++c)
#pragma unroll
                for (int n = 0; n < 8; ++n) c1[c][n] = fmaf(a1, p[c][n], c1[c][n]);
        }
    }

    // partials [fc][col][n]: thread's 4 cols x 8 n = 32 contiguous floats.
    float4* dst0 = reinterpret_cast<float4*>(p0 + ((size_t)fc * 8192 + col) * 8);
#pragma unroll
    for (int c = 0; c < 4; ++c) {
        dst0[2 * c + 0] = make_float4(c0[c][0], c0[c][1], c0[c][2], c0[c][3]);
        dst0[2 * c + 1] = make_float4(c0[c][4], c0[c][5], c0[c][6], c0[c][7]);
    }
    if constexpr (PASS_A) {
        float4* dst1 = reinterpret_cast<float4*>(p1 + ((size_t)fc * 8192 + col) * 8);
#pragma unroll
        for (int c = 0; c < 4; ++c) {
            dst1[2 * c + 0] = make_float4(c1[c][0], c1[c][1], c1[c][2], c1[c][3]);
            dst1[2 * c + 1] = make_float4(c1[c][4], c1[c][5], c1[c][6], c1[c][7]);
        }
    }
}

// K2: reduce c0 partials over 64 chunks, LayerNorm over o, write h1 in
// xT-compatible layout: xT2[f=g][d=o][n]  (fp32)
__global__ __launch_bounds__(128)
void k_reduce_ln(const float* __restrict__ part, float* __restrict__ outT) {
    __shared__ float sh[16][8];
    int g = blockIdx.x;                 // 0..511
    int t = threadIdx.x;                // 0..127
    int o = t >> 3, n = t & 7;
    size_t base = ((size_t)g * 16 + o) * 8 + n;
    float s0 = 0.f, s1 = 0.f, s2 = 0.f, s3 = 0.f;
#pragma unroll
    for (int ch = 0; ch < NFCH; ch += 4) {
        s0 += part[(size_t)(ch + 0) * 65536 + base];
        s1 += part[(size_t)(ch + 1) * 65536 + base];
        s2 += part[(size_t)(ch + 2) * 65536 + base];
        s3 += part[(size_t)(ch + 3) * 65536 + base];
    }
    float s = (s0 + s1) + (s2 + s3);
    sh[o][n] = s;
    __syncthreads();
    float m = 0.f, v = 0.f;
#pragma unroll
    for (int oo = 0; oo < 16; ++oo) { float y = sh[oo][n]; m += y; v += y * y; }
    m *= (1.f / 16.f);
    v = v * (1.f / 16.f) - m * m;
    float r = rsqrtf(v + 1e-5f);
    outT[base] = (s - m) * r;
}

// K4: y = 0.5*(c1+c2) (reduced over chunks), LayerNorm over o, fp32 out [n][o][g]
__global__ __launch_bounds__(128)
void k_final(const float* __restrict__ p1, const float* __restrict__ p2,
             float* __restrict__ out) {
    __shared__ float sh[16][8];
    int g = blockIdx.x;
    int t = threadIdx.x;
    int o = t >> 3, n = t & 7;
    size_t base = ((size_t)g * 16 + o) * 8 + n;
    float s0 = 0.f, s1 = 0.f, s2 = 0.f, s3 = 0.f;
#pragma unroll
    for (int ch = 0; ch < NFCH; ch += 2) {
        size_t i0 = (size_t)(ch + 0) * 65536 + base;
        size_t i1 = (size_t)(ch + 1) * 65536 + base;
        s0 += p1[i0]; s1 += p2[i0];
        s2 += p1[i1]; s3 += p2[i1];
    }
    float s = 0.5f * ((s0 + s1) + (s2 + s3));
    sh[o][n] = s;
    __syncthreads();
    float m = 0.f, v = 0.f;
#pragma unroll
    for (int oo = 0; oo < 16; ++oo) { float y = sh[oo][n]; m += y; v += y * y; }
    m *= (1.f / 16.f);
    v = v * (1.f / 16.f) - m * m;
    float r = rsqrtf(v + 1e-5f);
    out[n * 8192 + o * 512 + g] = (s - m) * r;
}

extern "C" void kernel_launch(void* const* d_in, const int* in_sizes, int n_in,
                              void* d_out, int out_size, void* d_ws, size_t ws_size,
                              hipStream_t stream) {
    const float* x = (const float*)d_in[0];   // (8,16,512)      fp32
    const float* W = (const float*)d_in[1];   // (16,512,512,16) fp32
    const float* A = (const float*)d_in[2];   // (2,512,512)     fp32
    float* out = (float*)d_out;               // (8,16,512)      fp32

    float* ws  = (float*)d_ws;
    float* xT  = ws;                    //   65536 floats: x  transposed [f][d][n]
    float* xT2 = ws + 65536;            //   65536 floats: h1 transposed [f][d][n]
    float* c0p = ws + 131072;           // 4194304 floats: c0 partials [64][8192][8]
    float* c1p = c0p + 4194304;         // 4194304 floats: c1 partials
    float* c2p = c1p + 4194304;         // 4194304 floats: c2 partials
    // total ws use: ~51 MB

    k0_prep_x<<<256, 256, 0, stream>>>(x, xT);
    k_contract<true ><<<dim3(NFCH, 8), 256, 0, stream>>>(W, A, xT,  c0p, c1p);
    k_reduce_ln<<<512, 128, 0, stream>>>(c0p, xT2);
    k_contract<false><<<dim3(NFCH, 8), 256, 0, stream>>>(W, A, xT2, c2p, nullptr);
    k_final<<<512, 128, 0, stream>>>(c1p, c2p, out);
}

// Round 7
// 464.015 us; speedup vs baseline: 1.2620x; 1.0941x over previous
//
#include <hip/hip_runtime.h>
#include <stdint.h>

// Problem: N=8, d=o=16, F=512, NUM_LAYERS=3.  ALL fp32 (per reference).
// out[n,o,g] = LN_o( 0.5*(c1 + c2) )  where
//   c0 = einsum(x, W, A0); h1 = LN_o(c0)
//   c1 = einsum(x, W, A1); c2 = einsum(h1, W, A0)
// einsum(h,W,a)[n,o,g] = sum_{d,f} h[n,d,f] * W[d,f,g,o] * a[f,g]
// W (fp32) is 256 MB -> two streaming passes (c0+c1 share pass 1).
// Roofline: 2 x 256 MB at ~6.3 TB/s ~= 82 us + small kernels.
//
// Ladder (per contract pass):
//  R1 222us: reg-cap spills.  R2 150us / R3 145us / R5 ~150us: all variants
//  of {W feed, x feed, cols/thread} identical ~1.7 TB/s.  R4 193us: barriers.
//  R6: crashed — A-staging loop wrote sA[fl] for fl up to 63 (LDS OOB).
// Theory under test (R6, never actually measured): the never-varied constant
//  across R0-R5 is the address pattern — 16MB power-of-2 d-stride and
//  4KB-aligned column windows alias HBM channels; all in-flight requests hit
//  a channel subset, capping the request stream (~one vmem/40cyc/CU = 1.7
//  TB/s). Sequential streams (fill kernel) get 6.7 TB/s on this box.
// R7 = R6 bugfixed: block owns (2d x 32f x 2048-col quarter); per iter the
//  block reads ONE 8KB contiguous chunk, advancing monotonically (32KB row
//  stride). Per thread-iter: 1 dwordx4 + 3 LDS reads + 36/72 VALU. x (1KB)
//  and A-slice (32KB) LDS-staged -> vmcnt queue carries W only.

#define FS   32    // f's per slab
#define NFS  16    // 512 / FS
#define DPG  2     // d's per block
#define NDG  8     // 16 / DPG
#define NSL  128   // NDG*NFS partial slices

// K0: x (fp32, [n][d][f]) -> xT (fp32, [f][d][n])  (65536 elems)
__global__ void k0_prep_x(const float* __restrict__ x, float* __restrict__ xT) {
    int idx = blockIdx.x * blockDim.x + threadIdx.x;   // 0..65535
    int n = idx & 7, d = (idx >> 3) & 15, f = idx >> 7;
    xT[idx] = x[n * 8192 + d * 512 + f];
}

// K1 (PASS_A=true):  c0 partials (A[0]) + c1 partials (A[1]) from xT
// K3 (PASS_A=false): c2 partials (A[0]) from xT2 (=h1 transposed)
// grid = (NFS=16, 4 col-quarters, NDG=8) = 512 blocks, 512 threads.
// Partial layout: [slice][col][n], slice = dg*NFS + fs.
template <bool PASS_A>
__global__ __launch_bounds__(512)
void k_contract(const float* __restrict__ W, const float* __restrict__ A,
                const float* __restrict__ xT,
                float* __restrict__ p0, float* __restrict__ p1) {
    __shared__ float sx[DPG][FS][8];     //  2 KB x slices [dd][f_local][n]
    __shared__ float sA[2][FS][128];     // 32 KB A slices [i][f_local][g_local]

    const int t  = threadIdx.x;          // 0..511
    const int fs = blockIdx.x;           // 0..15
    const int cq = blockIdx.y;           // 0..3
    const int dg = blockIdx.z;           // 0..7
    const int f0 = fs * FS;

    // ---- stage x: DPG*FS*8 = 512 floats, one per thread ----
    {
        int dd = t >> 8, fl = (t >> 3) & 31, n = t & 7;
        sx[dd][fl][n] = xT[(size_t)(f0 + fl) * 128 + (dg * DPG + dd) * 8 + n];
    }
    // ---- stage A slice(s): FS*128 = 4096 floats per mat = 1024 float4;
    //      512 threads x 2 float4 each (fl = flb, flb+16; fl < 32). ----
    {
        int gl = (t & 31) * 4, flb = t >> 5;          // flb 0..15
#pragma unroll
        for (int k = 0; k < 2; ++k) {
            int fl = flb + k * 16;                    // 0..31  (R6 bug: k<4 -> fl up to 63, LDS OOB)
            *reinterpret_cast<float4*>(&sA[0][fl][gl]) =
                *reinterpret_cast<const float4*>(&A[(size_t)(f0 + fl) * 512 + cq * 128 + gl]);
            if constexpr (PASS_A)
                *reinterpret_cast<float4*>(&sA[1][fl][gl]) =
                    *reinterpret_cast<const float4*>(&A[262144 + (size_t)(f0 + fl) * 512 + cq * 128 + gl]);
        }
    }
    __syncthreads();

    const int gl   = t >> 2;             // g_local 0..127
    const int col4 = cq * 2048 + t * 4;  // 4 consecutive cols, same g

    float c0[4][8], c1[4][8];
#pragma unroll
    for (int c = 0; c < 4; ++c)
#pragma unroll
        for (int n = 0; n < 8; ++n) { c0[c][n] = 0.f; c1[c][n] = 0.f; }

    // Block's W footprint: for each dd, [f0:f0+FS] x its 2048-col quarter.
    // Per iter the BLOCK reads 8KB contiguous (512 thr x 16B), advancing
    // monotonically in f (32KB row stride). No other vmem in the loop.
    const float* Wbase = W + (size_t)(dg * DPG) * 4194304 + (size_t)f0 * 8192 + col4;
#pragma unroll
    for (int dd = 0; dd < DPG; ++dd) {
        const float* Wd = Wbase + (size_t)dd * 4194304;
#pragma unroll 4
        for (int fl = 0; fl < FS; ++fl) {
            float4 w  = *reinterpret_cast<const float4*>(Wd + (size_t)fl * 8192);
            float4 xa = *reinterpret_cast<const float4*>(&sx[dd][fl][0]);
            float4 xb = *reinterpret_cast<const float4*>(&sx[dd][fl][4]);

            float a0 = sA[0][fl][gl];
            float4 w0 = make_float4(w.x * a0, w.y * a0, w.z * a0, w.w * a0);
#define FMA8(acc, c, wc) \
            acc[c][0] = fmaf(xa.x, wc, acc[c][0]); \
            acc[c][1] = fmaf(xa.y, wc, acc[c][1]); \
            acc[c][2] = fmaf(xa.z, wc, acc[c][2]); \
            acc[c][3] = fmaf(xa.w, wc, acc[c][3]); \
            acc[c][4] = fmaf(xb.x, wc, acc[c][4]); \
            acc[c][5] = fmaf(xb.y, wc, acc[c][5]); \
            acc[c][6] = fmaf(xb.z, wc, acc[c][6]); \
            acc[c][7] = fmaf(xb.w, wc, acc[c][7]);
            FMA8(c0, 0, w0.x)
            FMA8(c0, 1, w0.y)
            FMA8(c0, 2, w0.z)
            FMA8(c0, 3, w0.w)
            if constexpr (PASS_A) {
                float a1 = sA[1][fl][gl];
                float4 w1 = make_float4(w.x * a1, w.y * a1, w.z * a1, w.w * a1);
                FMA8(c1, 0, w1.x)
                FMA8(c1, 1, w1.y)
                FMA8(c1, 2, w1.z)
                FMA8(c1, 3, w1.w)
            }
#undef FMA8
        }
    }

    // partials [slice][col][n]: thread's 4 cols x 8 n = 32 contiguous floats;
    // wave writes 8KB contiguous.
    const int s = dg * NFS + fs;
    float* d0 = p0 + (size_t)s * 65536 + (size_t)col4 * 8;
#pragma unroll
    for (int c = 0; c < 4; ++c) {
        *reinterpret_cast<float4*>(d0 + c * 8 + 0) = make_float4(c0[c][0], c0[c][1], c0[c][2], c0[c][3]);
        *reinterpret_cast<float4*>(d0 + c * 8 + 4) = make_float4(c0[c][4], c0[c][5], c0[c][6], c0[c][7]);
    }
    if constexpr (PASS_A) {
        float* d1 = p1 + (size_t)s * 65536 + (size_t)col4 * 8;
#pragma unroll
        for (int c = 0; c < 4; ++c) {
            *reinterpret_cast<float4*>(d1 + c * 8 + 0) = make_float4(c1[c][0], c1[c][1], c1[c][2], c1[c][3]);
            *reinterpret_cast<float4*>(d1 + c * 8 + 4) = make_float4(c1[c][4], c1[c][5], c1[c][6], c1[c][7]);
        }
    }
}

// K2: reduce c0 partials over 128 slices, LayerNorm over o, write h1 in
// xT-compatible layout: xT2[f=g][d=o][n]  (fp32)
__global__ __launch_bounds__(128)
void k_reduce_ln(const float* __restrict__ part, float* __restrict__ outT) {
    __shared__ float sh[16][8];
    int g = blockIdx.x;                 // 0..511
    int t = threadIdx.x;                // 0..127
    int o = t >> 3, n = t & 7;
    size_t base = ((size_t)g * 16 + o) * 8 + n;
    float s0 = 0.f, s1 = 0.f, s2 = 0.f, s3 = 0.f;
#pragma unroll
    for (int ch = 0; ch < NSL; ch += 4) {
        s0 += part[(size_t)(ch + 0) * 65536 + base];
        s1 += part[(size_t)(ch + 1) * 65536 + base];
        s2 += part[(size_t)(ch + 2) * 65536 + base];
        s3 += part[(size_t)(ch + 3) * 65536 + base];
    }
    float s = (s0 + s1) + (s2 + s3);
    sh[o][n] = s;
    __syncthreads();
    float m = 0.f, v = 0.f;
#pragma unroll
    for (int oo = 0; oo < 16; ++oo) { float y = sh[oo][n]; m += y; v += y * y; }
    m *= (1.f / 16.f);
    v = v * (1.f / 16.f) - m * m;
    float r = rsqrtf(v + 1e-5f);
    outT[base] = (s - m) * r;
}

// K4: y = 0.5*(c1+c2) (reduced over slices), LayerNorm over o, fp32 out [n][o][g]
__global__ __launch_bounds__(128)
void k_final(const float* __restrict__ p1, const float* __restrict__ p2,
             float* __restrict__ out) {
    __shared__ float sh[16][8];
    int g = blockIdx.x;
    int t = threadIdx.x;
    int o = t >> 3, n = t & 7;
    size_t base = ((size_t)g * 16 + o) * 8 + n;
    float s0 = 0.f, s1 = 0.f, s2 = 0.f, s3 = 0.f;
#pragma unroll
    for (int ch = 0; ch < NSL; ch += 2) {
        size_t i0 = (size_t)(ch + 0) * 65536 + base;
        size_t i1 = (size_t)(ch + 1) * 65536 + base;
        s0 += p1[i0]; s1 += p2[i0];
        s2 += p1[i1]; s3 += p2[i1];
    }
    float s = 0.5f * ((s0 + s1) + (s2 + s3));
    sh[o][n] = s;
    __syncthreads();
    float m = 0.f, v = 0.f;
#pragma unroll
    for (int oo = 0; oo < 16; ++oo) { float y = sh[oo][n]; m += y; v += y * y; }
    m *= (1.f / 16.f);
    v = v * (1.f / 16.f) - m * m;
    float r = rsqrtf(v + 1e-5f);
    out[n * 8192 + o * 512 + g] = (s - m) * r;
}

extern "C" void kernel_launch(void* const* d_in, const int* in_sizes, int n_in,
                              void* d_out, int out_size, void* d_ws, size_t ws_size,
                              hipStream_t stream) {
    const float* x = (const float*)d_in[0];   // (8,16,512)      fp32
    const float* W = (const float*)d_in[1];   // (16,512,512,16) fp32
    const float* A = (const float*)d_in[2];   // (2,512,512)     fp32
    float* out = (float*)d_out;               // (8,16,512)      fp32

    float* ws  = (float*)d_ws;
    float* xT  = ws;                    //   65536 floats: x  transposed [f][d][n]
    float* xT2 = ws + 65536;            //   65536 floats: h1 transposed [f][d][n]
    float* c0p = ws + 131072;           // 8388608 floats: c0 partials [128][8192][8]
    float* c1p = c0p + 8388608;         // 8388608 floats: c1 partials
    float* c2p = c0p;                   // c0 buffer is dead after k_reduce_ln -> reuse
    // total ws use: ~64.5 MB

    k0_prep_x<<<256, 256, 0, stream>>>(x, xT);
    k_contract<true ><<<dim3(NFS, 4, NDG), 512, 0, stream>>>(W, A, xT,  c0p, c1p);
    k_reduce_ln<<<512, 128, 0, stream>>>(c0p, xT2);
    k_contract<false><<<dim3(NFS, 4, NDG), 512, 0, stream>>>(W, A, xT2, c2p, nullptr);
    k_final<<<512, 128, 0, stream>>>(c1p, c2p, out);
}

// Round 8
// 412.852 us; speedup vs baseline: 1.4184x; 1.1239x over previous
//
#include <hip/hip_runtime.h>
#include <stdint.h>

// Problem: N=8, d=o=16, F=512, NUM_LAYERS=3.  ALL fp32 (per reference).
// out[n,o,g] = LN_o( 0.5*(c1 + c2) )  where
//   c0 = einsum(x, W, A0); h1 = LN_o(c0)
//   c1 = einsum(x, W, A1); c2 = einsum(h1, W, A0)
// einsum(h,W,a)[n,o,g] = sum_{d,f} h[n,d,f] * W[d,f,g,o] * a[f,g]
// W (fp32) is 256 MB -> two streaming passes (c0+c1 share pass 1).
//
// R0-R7 finding: EVERY contract variant (load width 4/16B, 1/2/4 cols/thr,
// W via reg/LDS, x via s_load/LDS, 8-16 waves/CU, strided/sequential
// addressing) converges to ~150-160 us/pass. That is this box's empirical
// ceiling for fp32 stream+accumulate (~1.7-2 TB/s to consuming VALU; the
// 6.3 TB/s copy ceiling is read+write, ~3.1 TB/s read-side, and pays no
// accumulation dependency). Remaining recoverable time = launches + partial
// round-trips: R0 (best, 417) had ~80us of non-contract overhead; R7's
// bigger partials cost +47us.
// R8: 5 kernels -> 3. Fuse x-transpose into pass A prologue; fuse
// reduce+LN into pass B prologue (each block builds only its 32 h1 rows
// from the 4MB c0-partials, L2/L3-hot). Contract body = R0's proven one.

#define FC   32    // f's per chunk
#define NCH  16    // 512 / FC

// KA (SECOND=false): in = x (8,16,512); writes c0 partials (A0) + c1 (A1).
// KB (SECOND=true):  in = c0 partials; prologue reduces+LNs them into the
//                    32 h1 rows this block needs; writes c2 partials (A0).
// grid = (16 f-chunks, 32 col-tiles), 256 threads, 1 col/thread.
// Partial layout: [chunk][g][o][n] = [chunk][col][n], col = g*16+o.
template <bool SECOND>
__global__ __launch_bounds__(256)
void k_contract(const float* __restrict__ W, const float* __restrict__ A,
                const float* __restrict__ in,
                float* __restrict__ p0, float* __restrict__ p1) {
    __shared__ float sx[FC][16][8];   // 16 KB: h slices [f_local][d][n]
    __shared__ float sA0[FC][16];     //  2 KB: A0 [f_local][g_local]
    __shared__ float sA1[FC][16];     //  2 KB: A1 (pass A only)

    const int t  = threadIdx.x;       // 0..255
    const int fc = blockIdx.x;        // 0..15
    const int ct = blockIdx.y;        // 0..31
    const int f0 = fc * FC;

    if constexpr (!SECOND) {
        // ---- prologue A: transpose x slice into LDS (4096 vals, 16/thr).
        // x is 256 KB total -> L2/L3-hot after the first blocks.
#pragma unroll
        for (int k = 0; k < 16; ++k) {
            int idx = k * 256 + t;                 // 0..4095
            int fl = idx >> 7, d = (idx >> 3) & 15, n = idx & 7;
            sx[fl][d][n] = in[n * 8192 + d * 512 + f0 + fl];
        }
    } else {
        // ---- prologue B: build h1 rows g=f0..f0+31 from c0 partials.
        // step 1: chunk-sum (4096 vals, 16/thr; reads 256KB, L2/L3-hot)
#pragma unroll
        for (int k = 0; k < 16; ++k) {
            int idx = k * 256 + t;
            int fl = idx >> 7, o = (idx >> 3) & 15, n = idx & 7;
            float s = 0.f;
#pragma unroll
            for (int ch = 0; ch < NCH; ++ch)
                s += in[(((size_t)ch * 512 + f0 + fl) * 16 + o) * 8 + n];
            sx[fl][o][n] = s;
        }
        __syncthreads();
        // step 2: LayerNorm over o, in place. Thread owns (fl,n) column ->
        // exclusive access to sx[fl][*][n]; no race after the barrier.
        {
            int fl = t >> 3, n = t & 7;            // 32*8 = 256 = blockDim
            float m = 0.f, v = 0.f;
#pragma unroll
            for (int oo = 0; oo < 16; ++oo) { float y = sx[fl][oo][n]; m += y; v += y * y; }
            m *= (1.f / 16.f);
            v = v * (1.f / 16.f) - m * m;
            float r = rsqrtf(v + 1e-5f);
#pragma unroll
            for (int oo = 0; oo < 16; ++oo) sx[fl][oo][n] = (sx[fl][oo][n] - m) * r;
        }
    }
    // ---- stage A slices: 512 vals per mat, 2/thr ----
    {
#pragma unroll
        for (int k = 0; k < 2; ++k) {
            int idx = k * 256 + t;                 // 0..511
            int fl = idx >> 4, gl = idx & 15;
            sA0[fl][gl] = A[(size_t)(f0 + fl) * 512 + ct * 16 + gl];
            if constexpr (!SECOND)
                sA1[fl][gl] = A[262144 + (size_t)(f0 + fl) * 512 + ct * 16 + gl];
        }
    }
    __syncthreads();

    // ---- main loop: R0's proven contract body (x/A from LDS) ----
    const int gl  = t >> 4;            // g_local 0..15
    const int o   = t & 15;
    const int col = (ct * 16 + gl) * 16 + o;
    const float* Wc = W + col;         // + d*4194304 + f*8192

    float c0[8], c1[8];
#pragma unroll
    for (int n = 0; n < 8; ++n) { c0[n] = 0.f; c1[n] = 0.f; }

    for (int fl = 0; fl < FC; ++fl) {
        const int f = f0 + fl;
        float w[16];
#pragma unroll
        for (int d = 0; d < 16; ++d)
            w[d] = Wc[(size_t)d * 4194304 + (size_t)f * 8192];

        float p[8];
#pragma unroll
        for (int n = 0; n < 8; ++n) p[n] = 0.f;
#pragma unroll
        for (int d = 0; d < 16; ++d) {
            float4 xa = *reinterpret_cast<const float4*>(&sx[fl][d][0]);
            float4 xb = *reinterpret_cast<const float4*>(&sx[fl][d][4]);
            p[0] = fmaf(xa.x, w[d], p[0]);
            p[1] = fmaf(xa.y, w[d], p[1]);
            p[2] = fmaf(xa.z, w[d], p[2]);
            p[3] = fmaf(xa.w, w[d], p[3]);
            p[4] = fmaf(xb.x, w[d], p[4]);
            p[5] = fmaf(xb.y, w[d], p[5]);
            p[6] = fmaf(xb.z, w[d], p[6]);
            p[7] = fmaf(xb.w, w[d], p[7]);
        }

        const float a0 = sA0[fl][gl];
#pragma unroll
        for (int n = 0; n < 8; ++n) c0[n] = fmaf(a0, p[n], c0[n]);
        if constexpr (!SECOND) {
            const float a1 = sA1[fl][gl];
#pragma unroll
            for (int n = 0; n < 8; ++n) c1[n] = fmaf(a1, p[n], c1[n]);
        }
    }

    // partials [chunk][col][n]: thread's 8 floats contiguous, coalesced.
    size_t base = ((size_t)fc * 8192 + col) * 8;
    float4* dst0 = reinterpret_cast<float4*>(p0 + base);
    dst0[0] = make_float4(c0[0], c0[1], c0[2], c0[3]);
    dst0[1] = make_float4(c0[4], c0[5], c0[6], c0[7]);
    if constexpr (!SECOND) {
        float4* dst1 = reinterpret_cast<float4*>(p1 + base);
        dst1[0] = make_float4(c1[0], c1[1], c1[2], c1[3]);
        dst1[1] = make_float4(c1[4], c1[5], c1[6], c1[7]);
    }
}

// KF: y = 0.5*(c1+c2) reduced over 16 chunks, LayerNorm over o, out [n][o][g]
__global__ __launch_bounds__(128)
void k_final(const float* __restrict__ p1, const float* __restrict__ p2,
             float* __restrict__ out) {
    __shared__ float sh[16][8];
    int g = blockIdx.x;                 // 0..511
    int t = threadIdx.x;                // 0..127
    int o = t >> 3, n = t & 7;
    float s0 = 0.f, s1 = 0.f;
#pragma unroll
    for (int ch = 0; ch < NCH; ++ch) {
        size_t idx = (((size_t)ch * 512 + g) * 16 + o) * 8 + n;
        s0 += p1[idx];
        s1 += p2[idx];
    }
    float s = 0.5f * (s0 + s1);
    sh[o][n] = s;
    __syncthreads();
    float m = 0.f, v = 0.f;
#pragma unroll
    for (int oo = 0; oo < 16; ++oo) { float y = sh[oo][n]; m += y; v += y * y; }
    m *= (1.f / 16.f);
    v = v * (1.f / 16.f) - m * m;
    float r = rsqrtf(v + 1e-5f);
    out[n * 8192 + o * 512 + g] = (s - m) * r;
}

extern "C" void kernel_launch(void* const* d_in, const int* in_sizes, int n_in,
                              void* d_out, int out_size, void* d_ws, size_t ws_size,
                              hipStream_t stream) {
    const float* x = (const float*)d_in[0];   // (8,16,512)      fp32
    const float* W = (const float*)d_in[1];   // (16,512,512,16) fp32
    const float* A = (const float*)d_in[2];   // (2,512,512)     fp32
    float* out = (float*)d_out;               // (8,16,512)      fp32

    float* ws  = (float*)d_ws;
    float* c0p = ws;                    // 1048576 floats: c0 partials [16][8192][8]
    float* c1p = c0p + 1048576;         // 1048576 floats: c1 partials
    float* c2p = c1p + 1048576;         // 1048576 floats: c2 partials
    // total ws use: 12 MB

    k_contract<false><<<dim3(NCH, 32), 256, 0, stream>>>(W, A, x,   c0p, c1p);
    k_contract<true ><<<dim3(NCH, 32), 256, 0, stream>>>(W, A, c0p, c2p, nullptr);
    k_final<<<512, 128, 0, stream>>>(c1p, c2p, out);
}